// Round 7
// baseline (3949.603 us; speedup 1.0000x reference)
//
#include <hip/hip_runtime.h>
#include <hip/hip_bf16.h>
#include <stdint.h>

#define N_NODES 50000
#define N_EDGES 800000

typedef unsigned int uint32;

__device__ __forceinline__ float bf_lo(uint32 u) { return __uint_as_float(u << 16); }
__device__ __forceinline__ float bf_hi(uint32 u) { return __uint_as_float(u & 0xffff0000u); }
__device__ __forceinline__ float silu(float v) { return v / (1.0f + __expf(-v)); }
__device__ __forceinline__ uint32 pk_bf(float lo, float hi) {
    union { __hip_bfloat16 b[2]; uint32 u; } z;
    z.b[0] = __float2bfloat16(lo); z.b[1] = __float2bfloat16(hi);
    return z.u;
}

// ---------- Kernel 0: zero the aggregation buffers --------------------------
__global__ __launch_bounds__(256) void zero_ws(float* __restrict__ p, int n) {
    int i = blockIdx.x * 256 + threadIdx.x;
    int stride = gridDim.x * 256;
    for (; i < n; i += stride) p[i] = 0.0f;
}

// ---------- Kernel 1: A = h@W1[0:128], B = h@W1[128:256]  (1 node/wave) -----
__global__ __launch_bounds__(256) void pre_proj(
    const float* __restrict__ h, const float* __restrict__ W1,
    uint32* __restrict__ A, uint32* __restrict__ B)
{
    const int lane = threadIdx.x & 63;
    const int n = blockIdx.x * 4 + (threadIdx.x >> 6);
    if (n >= N_NODES) return;
    const int j0 = lane * 2;

    const float ha = h[(size_t)n * 128 + lane];        // h[n][lane]
    const float hb = h[(size_t)n * 128 + 64 + lane];   // h[n][64+lane]

    float a0 = 0.f, a1 = 0.f, b0 = 0.f, b1 = 0.f;
#pragma unroll 8
    for (int k = 0; k < 64; ++k) {
        const float va = __shfl(ha, k);                // h[n][k]
        const float vb = __shfl(hb, k);                // h[n][64+k]
        const float2 wa0 = *(const float2*)(W1 + (size_t)k * 128 + j0);
        const float2 wa1 = *(const float2*)(W1 + (size_t)(64 + k) * 128 + j0);
        const float2 wb0 = *(const float2*)(W1 + (size_t)(128 + k) * 128 + j0);
        const float2 wb1 = *(const float2*)(W1 + (size_t)(192 + k) * 128 + j0);
        a0 += va * wa0.x + vb * wa1.x;
        a1 += va * wa0.y + vb * wa1.y;
        b0 += va * wb0.x + vb * wb1.x;
        b1 += va * wb0.y + vb * wb1.y;
    }
    A[(size_t)n * 64 + lane] = pk_bf(a0, a1);
    B[(size_t)n * 64 + lane] = pk_bf(b0, b1);
}

// ---------- Kernel 2: edge MLP + scatter ------------------------------------
// LDS = exactly 64 KiB (sW2 + sWc1, bf16x2). Small params in registers.
#define EB 512
__global__ __launch_bounds__(EB) void edge_kernel(
    const int* __restrict__ ei, const float* __restrict__ x,
    const float* __restrict__ eattr,
    const float* __restrict__ W1, const float* __restrict__ b1,
    const float* __restrict__ W2, const float* __restrict__ b2,
    const float* __restrict__ Wc1, const float* __restrict__ bc1,
    const float* __restrict__ Wc2, const float* __restrict__ bc2,
    const uint32* __restrict__ A, const uint32* __restrict__ B,
    float* __restrict__ agg_msg, float* __restrict__ agg_coord, float* __restrict__ cnt)
{
    __shared__ uint32 sW2[128 * 64];    // i=k*64+p -> (W2[k][2p], W2[k][2p+1])
    __shared__ uint32 sWc1[128 * 64];

    const int tid = threadIdx.x;
    for (int i = tid; i < 128 * 64; i += EB) {
        const int k = i >> 6, c = (i & 63) * 2;
        sW2[i]  = pk_bf(W2[(size_t)k * 128 + c],  W2[(size_t)k * 128 + c + 1]);
        sWc1[i] = pk_bf(Wc1[(size_t)k * 128 + c], Wc1[(size_t)k * 128 + c + 1]);
    }

    const int lane = tid & 63;
    const int j0   = lane * 2;
    const float2 w1e0 = *(const float2*)(W1 + 256 * 128 + j0);
    const float2 w1e1 = *(const float2*)(W1 + 257 * 128 + j0);
    const float2 w1e2 = *(const float2*)(W1 + 258 * 128 + j0);
    const float2 w1d  = *(const float2*)(W1 + 259 * 128 + j0);
    const float2 b1v  = *(const float2*)(b1 + j0);
    const float2 b2v  = *(const float2*)(b2 + j0);
    const float2 bc1v = *(const float2*)(bc1 + j0);
    const float2 wc2v = *(const float2*)(Wc2 + j0);
    const float  bc2f = bc2[0];

    __syncthreads();

    const int wave = blockIdx.x * (EB / 64) + (tid >> 6);
    const int nw   = gridDim.x * (EB / 64);

    for (int e = wave; e < N_EDGES; e += nw) {
        const int src = ei[e];
        const int dst = ei[N_EDGES + e];
        const float rx = x[src * 3 + 0] - x[dst * 3 + 0];
        const float ry = x[src * 3 + 1] - x[dst * 3 + 1];
        const float rz = x[src * 3 + 2] - x[dst * 3 + 2];
        const float dsq = rx * rx + ry * ry + rz * rz;
        const float ea0 = eattr[(size_t)e * 3 + 0];
        const float ea1 = eattr[(size_t)e * 3 + 1];
        const float ea2 = eattr[(size_t)e * 3 + 2];

        const uint32 av = A[(size_t)src * 64 + lane];
        const uint32 bv = B[(size_t)dst * 64 + lane];
        float p0 = bf_lo(av) + bf_lo(bv) + ea0 * w1e0.x + ea1 * w1e1.x
                 + ea2 * w1e2.x + dsq * w1d.x + b1v.x;
        float p1 = bf_hi(av) + bf_hi(bv) + ea0 * w1e0.y + ea1 * w1e1.y
                 + ea2 * w1e2.y + dsq * w1d.y + b1v.y;
        float m1x = silu(p0), m1y = silu(p1);   // lane l holds m1[2l], m1[2l+1]

        // m2 = silu(m1 @ W2 + b2)
        float c0 = b2v.x, c1 = b2v.y;
#pragma unroll 8
        for (int q = 0; q < 64; ++q) {
            const float va = __shfl(m1x, q);    // m1[2q]
            const float vb = __shfl(m1y, q);    // m1[2q+1]
            const uint32 w0 = sW2[(2 * q) * 64 + lane];
            const uint32 w1 = sW2[(2 * q + 1) * 64 + lane];
            c0 += va * bf_lo(w0) + vb * bf_lo(w1);
            c1 += va * bf_hi(w0) + vb * bf_hi(w1);
        }
        float m2x = silu(c0), m2y = silu(c1);

        // t = silu(m2 @ Wc1 + bc1)
        float t0 = bc1v.x, t1 = bc1v.y;
#pragma unroll 8
        for (int q = 0; q < 64; ++q) {
            const float va = __shfl(m2x, q);
            const float vb = __shfl(m2y, q);
            const uint32 w0 = sWc1[(2 * q) * 64 + lane];
            const uint32 w1 = sWc1[(2 * q + 1) * 64 + lane];
            t0 += va * bf_lo(w0) + vb * bf_lo(w1);
            t1 += va * bf_hi(w0) + vb * bf_hi(w1);
        }
        t0 = silu(t0); t1 = silu(t1);

        // coord_w = t . Wc2 + bc2  (wave reduction)
        float tw = t0 * wc2v.x + t1 * wc2v.y;
#pragma unroll
        for (int off = 32; off; off >>= 1) tw += __shfl_xor(tw, off);
        const float cw = tw + bc2f;

        atomicAdd(&agg_msg[(size_t)dst * 128 + j0],     m2x);
        atomicAdd(&agg_msg[(size_t)dst * 128 + j0 + 1], m2y);
        if (lane < 3) {
            const float r = (lane == 0) ? rx : ((lane == 1) ? ry : rz);
            atomicAdd(&agg_coord[dst * 3 + lane], r * cw);
        } else if (lane == 3) {
            atomicAdd(&cnt[dst], 1.0f);
        }
    }
}

// ---------- Kernel 3: node MLP + layernorm + x_out  (1 node/wave) -----------
// OUTPUT IS FLOAT32 (reference returns float32; "bf16" in the test label is
// literal text, not a dtype probe — rounds 3-6 failed on bf16-packed writes).
__global__ __launch_bounds__(256) void node_kernel(
    const float* __restrict__ h, const float* __restrict__ x,
    const float* __restrict__ Wn1, const float* __restrict__ bn1,
    const float* __restrict__ Wn2, const float* __restrict__ bn2,
    const float* __restrict__ gamma, const float* __restrict__ beta,
    const float* __restrict__ agg_msg, const float* __restrict__ agg_coord,
    const float* __restrict__ cnt, float* __restrict__ out)
{
    const int lane = threadIdx.x & 63;
    const int n = blockIdx.x * 4 + (threadIdx.x >> 6);
    if (n >= N_NODES) return;
    const int j0 = lane * 2;

    const float r0 = h[(size_t)n * 128 + lane];            // node_in[lane]
    const float r1 = h[(size_t)n * 128 + 64 + lane];       // node_in[64+lane]
    const float r2 = agg_msg[(size_t)n * 128 + lane];      // node_in[128+lane]
    const float r3 = agg_msg[(size_t)n * 128 + 64 + lane]; // node_in[192+lane]

    const float2 bn1v = *(const float2*)(bn1 + j0);
    float a0 = bn1v.x, a1 = bn1v.y;
#pragma unroll 8
    for (int k = 0; k < 64; ++k) {
        const float v0 = __shfl(r0, k);
        const float v1 = __shfl(r1, k);
        const float v2 = __shfl(r2, k);
        const float v3 = __shfl(r3, k);
        const float2 w0 = *(const float2*)(Wn1 + (size_t)k * 128 + j0);
        const float2 w1 = *(const float2*)(Wn1 + (size_t)(64 + k) * 128 + j0);
        const float2 w2 = *(const float2*)(Wn1 + (size_t)(128 + k) * 128 + j0);
        const float2 w3 = *(const float2*)(Wn1 + (size_t)(192 + k) * 128 + j0);
        a0 += v0 * w0.x + v1 * w1.x + v2 * w2.x + v3 * w3.x;
        a1 += v0 * w0.y + v1 * w1.y + v2 * w2.y + v3 * w3.y;
    }
    const float z0 = silu(a0), z1 = silu(a1);   // lane l holds z[2l], z[2l+1]

    const float2 bn2v = *(const float2*)(bn2 + j0);
    float u0 = bn2v.x, u1 = bn2v.y;
#pragma unroll 8
    for (int q = 0; q < 64; ++q) {
        const float va = __shfl(z0, q);         // z[2q]
        const float vb = __shfl(z1, q);         // z[2q+1]
        const float2 w0 = *(const float2*)(Wn2 + (size_t)(2 * q) * 128 + j0);
        const float2 w1 = *(const float2*)(Wn2 + (size_t)(2 * q + 1) * 128 + j0);
        u0 += va * w0.x + vb * w1.x;
        u1 += va * w0.y + vb * w1.y;
    }

    const float2 hv = *(const float2*)(h + (size_t)n * 128 + j0);
    const float y0 = hv.x + u0;
    const float y1 = hv.y + u1;
    float s1 = y0 + y1, s2 = y0 * y0 + y1 * y1;
#pragma unroll
    for (int off = 32; off; off >>= 1) { s1 += __shfl_xor(s1, off); s2 += __shfl_xor(s2, off); }
    const float mu  = s1 * (1.0f / 128.0f);
    const float var = s2 * (1.0f / 128.0f) - mu * mu;
    const float rs  = rsqrtf(var + 1e-5f);
    const float2 gv = *(const float2*)(gamma + j0);
    const float2 bv = *(const float2*)(beta + j0);
    float2 o;
    o.x = (y0 - mu) * rs * gv.x + bv.x;
    o.y = (y1 - mu) * rs * gv.y + bv.y;
    *(float2*)(out + (size_t)n * 128 + j0) = o;

    if (lane < 3) {
        const float c = fmaxf(cnt[n], 1.0f);
        out[(size_t)N_NODES * 128 + (size_t)n * 3 + lane] =
            x[n * 3 + lane] + agg_coord[n * 3 + lane] / c;
    }
}

extern "C" void kernel_launch(void* const* d_in, const int* in_sizes, int n_in,
                              void* d_out, int out_size, void* d_ws, size_t ws_size,
                              hipStream_t stream)
{
    const float* h     = (const float*)d_in[0];
    const float* x     = (const float*)d_in[1];
    const int*   ei    = (const int*)d_in[2];
    const float* eattr = (const float*)d_in[3];
    const float* W1    = (const float*)d_in[4];
    const float* b1    = (const float*)d_in[5];
    const float* W2    = (const float*)d_in[6];
    const float* b2    = (const float*)d_in[7];
    const float* Wc1   = (const float*)d_in[8];
    const float* bc1   = (const float*)d_in[9];
    const float* Wc2   = (const float*)d_in[10];
    const float* bc2   = (const float*)d_in[11];
    const float* Wn1   = (const float*)d_in[12];
    const float* bn1   = (const float*)d_in[13];
    const float* Wn2   = (const float*)d_in[14];
    const float* bn2   = (const float*)d_in[15];
    const float* gamma = (const float*)d_in[16];
    const float* beta  = (const float*)d_in[17];

    // ws layout (52.0 MB):
    //   A        : N*64 uint32 (bf16x2)
    //   B        : N*64 uint32 (bf16x2)
    //   agg_msg  : N*128 f32 (zeroed)
    //   agg_coord: N*3 f32   (zeroed)
    //   cnt      : N f32     (zeroed)
    uint32* A        = (uint32*)d_ws;
    uint32* B        = A + (size_t)N_NODES * 64;
    float* agg_msg   = (float*)(B + (size_t)N_NODES * 64);
    float* agg_coord = agg_msg + (size_t)N_NODES * 128;
    float* cnt       = agg_coord + (size_t)N_NODES * 3;

    const int zero_elems = N_NODES * 128 + N_NODES * 3 + N_NODES;
    zero_ws<<<512, 256, 0, stream>>>(agg_msg, zero_elems);

    pre_proj<<<(N_NODES + 3) / 4, 256, 0, stream>>>(h, W1, A, B);
    edge_kernel<<<512, EB, 0, stream>>>(ei, x, eattr, W1, b1, W2, b2, Wc1, bc1,
                                        Wc2, bc2, A, B, agg_msg, agg_coord, cnt);
    node_kernel<<<(N_NODES + 3) / 4, 256, 0, stream>>>(h, x, Wn1, bn1, Wn2, bn2,
                                                       gamma, beta, agg_msg, agg_coord,
                                                       cnt, (float*)d_out);
}

// Round 9
// 2467.058 us; speedup vs baseline: 1.6009x; 1.6009x over previous
//
#include <hip/hip_runtime.h>
#include <hip/hip_bf16.h>
#include <stdint.h>

#define N_NODES 50000
#define N_EDGES 800000
#define N_TILES (N_EDGES / 16)

typedef unsigned int uint32;
typedef __fp16   fp16x2 __attribute__((ext_vector_type(2)));
typedef _Float16 half8v __attribute__((ext_vector_type(8)));
typedef float    f32x4  __attribute__((ext_vector_type(4)));
typedef uint32   u32x2  __attribute__((ext_vector_type(2)));
typedef uint32   u32x4  __attribute__((ext_vector_type(4)));

union H2U { uint32 u; fp16x2 h; };
union H8U { u32x4 u; half8v h; };

__device__ __forceinline__ uint32 pk16(float lo, float hi) {
    H2U z; z.h = __builtin_amdgcn_cvt_pkrtz(lo, hi); return z.u;
}
__device__ __forceinline__ float h16lo(uint32 u) { H2U z; z.u = u; return (float)z.h[0]; }
__device__ __forceinline__ float h16hi(uint32 u) { H2U z; z.u = u; return (float)z.h[1]; }
__device__ __forceinline__ float silu(float v) { return v / (1.0f + __expf(-v)); }

// ---------- Kernel 0: zero aggregation buffers ------------------------------
__global__ __launch_bounds__(256) void zero_ws(float* __restrict__ p, int n) {
    int i = blockIdx.x * 256 + threadIdx.x;
    int stride = gridDim.x * 256;
    for (; i < n; i += stride) p[i] = 0.0f;
}

// ---------- Kernel 0b: build W2^T / Wc1^T A-fragments (f16x2) in ws ---------
// Frag f = ot*4+kb; entry ((f*64+lane)*4+p) = (W[k0][o], W[k0+1][o]),
// k0 = kb*32 + (lane>>4)*8 + 2p, o = (lane&15) + 16*ot.  8192 uints each.
__global__ __launch_bounds__(256) void prep_frags(
    const float* __restrict__ W2, const float* __restrict__ Wc1,
    uint32* __restrict__ W2A, uint32* __restrict__ WC1A)
{
    int i = blockIdx.x * 256 + threadIdx.x;
    if (i >= 8192) return;
    const int p = i & 3, l = (i >> 2) & 63, f = i >> 8;
    const int ot = f >> 2, kb = f & 3;
    const int k0 = kb * 32 + (l >> 4) * 8 + 2 * p;
    const int o  = (l & 15) + ot * 16;
    W2A[i]  = pk16(W2[(size_t)k0 * 128 + o],  W2[(size_t)(k0 + 1) * 128 + o]);
    WC1A[i] = pk16(Wc1[(size_t)k0 * 128 + o], Wc1[(size_t)(k0 + 1) * 128 + o]);
}

// ---------- Kernel 1: A = h@W1[0:128], B = h@W1[128:256] (f16x2 packed) -----
__global__ __launch_bounds__(256) void pre_proj(
    const float* __restrict__ h, const float* __restrict__ W1,
    uint32* __restrict__ A, uint32* __restrict__ B)
{
    const int lane = threadIdx.x & 63;
    const int n = blockIdx.x * 4 + (threadIdx.x >> 6);
    if (n >= N_NODES) return;
    const int j0 = lane * 2;

    const float ha = h[(size_t)n * 128 + lane];
    const float hb = h[(size_t)n * 128 + 64 + lane];

    float a0 = 0.f, a1 = 0.f, b0 = 0.f, b1 = 0.f;
#pragma unroll 8
    for (int k = 0; k < 64; ++k) {
        const float va = __shfl(ha, k);
        const float vb = __shfl(hb, k);
        const float2 wa0 = *(const float2*)(W1 + (size_t)k * 128 + j0);
        const float2 wa1 = *(const float2*)(W1 + (size_t)(64 + k) * 128 + j0);
        const float2 wb0 = *(const float2*)(W1 + (size_t)(128 + k) * 128 + j0);
        const float2 wb1 = *(const float2*)(W1 + (size_t)(192 + k) * 128 + j0);
        a0 += va * wa0.x + vb * wa1.x;
        a1 += va * wa0.y + vb * wa1.y;
        b0 += va * wb0.x + vb * wb1.x;
        b1 += va * wb0.y + vb * wb1.y;
    }
    A[(size_t)n * 64 + lane] = pk16(a0, a1);
    B[(size_t)n * 64 + lane] = pk16(b0, b1);
}

// ---------- Kernel 2: MFMA edge kernel --------------------------------------
// 16 edges per wave-tile. m1 built scalar (lane = ch 2l,2l+1), staged to LDS
// as f16, read back as MFMA B-frags. D = W^T(A-frag, from ws) x m1^T(B-frag):
// C/D lane holds col e = lane&15, row o = 16*ot + 4*quad + r.
#define EWAVES 4
__global__ __launch_bounds__(256, 2) void edge_mfma(
    const int* __restrict__ ei, const float* __restrict__ x,
    const float* __restrict__ eattr,
    const float* __restrict__ W1, const float* __restrict__ b1,
    const float* __restrict__ b2, const float* __restrict__ bc1,
    const float* __restrict__ Wc2, const float* __restrict__ bc2,
    const uint32* __restrict__ W2A, const uint32* __restrict__ WC1A,
    const uint32* __restrict__ Apk, const uint32* __restrict__ Bpk,
    float* __restrict__ agg_msg, float* __restrict__ agg_coord, float* __restrict__ cnt)
{
    __shared__ uint32 sM1[EWAVES * 16 * 68];   // 16 edges x 68-uint stride per wave

    const int tid  = threadIdx.x;
    const int lane = tid & 63;
    const int wv   = tid >> 6;
    const int quad = lane >> 4;
    const int e_own = lane & 15;
    const int swb  = wv * (16 * 68);
    const int j0   = lane * 2;

    // loop-invariant per-lane parameters
    const float2 w1e0 = *(const float2*)(W1 + 256 * 128 + j0);
    const float2 w1e1 = *(const float2*)(W1 + 257 * 128 + j0);
    const float2 w1e2 = *(const float2*)(W1 + 258 * 128 + j0);
    const float2 w1d  = *(const float2*)(W1 + 259 * 128 + j0);
    const float2 b1v  = *(const float2*)(b1 + j0);
    const float  bc2f = bc2[0];

    f32x4 b2r[8], bc1r[8], wc2r[8];
#pragma unroll
    for (int ot = 0; ot < 8; ++ot) {
        b2r[ot]  = *(const f32x4*)(b2  + 16 * ot + 4 * quad);
        bc1r[ot] = *(const f32x4*)(bc1 + 16 * ot + 4 * quad);
        wc2r[ot] = *(const f32x4*)(Wc2 + 16 * ot + 4 * quad);
    }

    const int wave = blockIdx.x * EWAVES + wv;
    const int nw   = gridDim.x * EWAVES;

    for (int tile = wave; tile < N_TILES; tile += nw) {
        const int ebase = tile * 16;
        const int eidx  = ebase + e_own;
        const int src_own = ei[eidx];
        const int dst_own = ei[N_EDGES + eidx];
        const float rxo = x[src_own * 3 + 0] - x[dst_own * 3 + 0];
        const float ryo = x[src_own * 3 + 1] - x[dst_own * 3 + 1];
        const float rzo = x[src_own * 3 + 2] - x[dst_own * 3 + 2];
        const float dsq = rxo * rxo + ryo * ryo + rzo * rzo;
        const float ea0 = eattr[(size_t)eidx * 3 + 0];
        const float ea1 = eattr[(size_t)eidx * 3 + 1];
        const float ea2 = eattr[(size_t)eidx * 3 + 2];

        // ---- phase 1: m1 for 16 edges, lane = channels (2l, 2l+1) ----------
#pragma unroll
        for (int e = 0; e < 16; ++e) {
            const int   srcE = __shfl(src_own, e);
            const int   dstE = __shfl(dst_own, e);
            const float de0 = __shfl(ea0, e);
            const float de1 = __shfl(ea1, e);
            const float de2 = __shfl(ea2, e);
            const float dq  = __shfl(dsq, e);
            const uint32 av = Apk[(size_t)srcE * 64 + lane];
            const uint32 bv = Bpk[(size_t)dstE * 64 + lane];
            const float p0 = h16lo(av) + h16lo(bv) + de0 * w1e0.x + de1 * w1e1.x
                           + de2 * w1e2.x + dq * w1d.x + b1v.x;
            const float p1 = h16hi(av) + h16hi(bv) + de0 * w1e0.y + de1 * w1e1.y
                           + de2 * w1e2.y + dq * w1d.y + b1v.y;
            sM1[swb + e * 68 + lane] = pk16(silu(p0), silu(p1));
        }

        // ---- B-frags of m1^T: lane holds m1[e_own][32kb + quad*8 + j] ------
        H8U m1f[4];
#pragma unroll
        for (int kb = 0; kb < 4; ++kb)
            m1f[kb].u = *(const u32x4*)&sM1[swb + e_own * 68 + kb * 16 + quad * 4];

        // ---- matmul 1: D1[o][e] = sum_k W2[k][o] * m1[e][k] ----------------
        f32x4 acc[8];
#pragma unroll
        for (int ot = 0; ot < 8; ++ot) acc[ot] = 0.0f;
#pragma unroll 2
        for (int ot = 0; ot < 8; ++ot) {
#pragma unroll
            for (int kb = 0; kb < 4; ++kb) {
                H8U w; w.u = *(const u32x4*)(W2A + (size_t)((ot * 4 + kb) * 64 + lane) * 4);
                acc[ot] = __builtin_amdgcn_mfma_f32_16x16x32_f16(w.h, m1f[kb].h, acc[ot], 0, 0, 0);
            }
        }

        // ---- epilogue 1: m2 = silu(D1 + b2); atomics + restage as f16 ------
        const size_t msg_base = (size_t)dst_own * 128 + 4 * quad;
#pragma unroll
        for (int ot = 0; ot < 8; ++ot) {
            const float m0 = silu(acc[ot][0] + b2r[ot][0]);
            const float m1_ = silu(acc[ot][1] + b2r[ot][1]);
            const float m2_ = silu(acc[ot][2] + b2r[ot][2]);
            const float m3_ = silu(acc[ot][3] + b2r[ot][3]);
            atomicAdd(&agg_msg[msg_base + 16 * ot + 0], m0);
            atomicAdd(&agg_msg[msg_base + 16 * ot + 1], m1_);
            atomicAdd(&agg_msg[msg_base + 16 * ot + 2], m2_);
            atomicAdd(&agg_msg[msg_base + 16 * ot + 3], m3_);
            u32x2 pair;
            pair[0] = pk16(m0, m1_);
            pair[1] = pk16(m2_, m3_);
            *(u32x2*)&sM1[swb + e_own * 68 + 8 * ot + 2 * quad] = pair;
        }

        // ---- B-frags of m2^T ----------------------------------------------
        H8U m2f[4];
#pragma unroll
        for (int kb = 0; kb < 4; ++kb)
            m2f[kb].u = *(const u32x4*)&sM1[swb + e_own * 68 + kb * 16 + quad * 4];

        // ---- matmul 2: D2[o2][e] = sum_k Wc1[k][o2] * m2[e][k] -------------
#pragma unroll
        for (int ot = 0; ot < 8; ++ot) acc[ot] = 0.0f;
#pragma unroll 2
        for (int ot = 0; ot < 8; ++ot) {
#pragma unroll
            for (int kb = 0; kb < 4; ++kb) {
                H8U w; w.u = *(const u32x4*)(WC1A + (size_t)((ot * 4 + kb) * 64 + lane) * 4);
                acc[ot] = __builtin_amdgcn_mfma_f32_16x16x32_f16(w.h, m2f[kb].h, acc[ot], 0, 0, 0);
            }
        }

        // ---- epilogue 2: t = silu(D2 + bc1); cw = t.Wc2 + bc2; coord -------
        float partial = 0.0f;
#pragma unroll
        for (int ot = 0; ot < 8; ++ot) {
#pragma unroll
            for (int r = 0; r < 4; ++r) {
                const float t = silu(acc[ot][r] + bc1r[ot][r]);
                partial += t * wc2r[ot][r];
            }
        }
        partial += __shfl_xor(partial, 16);
        partial += __shfl_xor(partial, 32);
        const float cw = partial + bc2f;

        if (quad < 3) {
            const float rsel = (quad == 0) ? rxo : ((quad == 1) ? ryo : rzo);
            atomicAdd(&agg_coord[dst_own * 3 + quad], rsel * cw);
        } else {
            atomicAdd(&cnt[dst_own], 1.0f);
        }
    }
}

// ---------- Kernel 3: node MLP + layernorm + x_out --------------------------
__global__ __launch_bounds__(256) void node_kernel(
    const float* __restrict__ h, const float* __restrict__ x,
    const float* __restrict__ Wn1, const float* __restrict__ bn1,
    const float* __restrict__ Wn2, const float* __restrict__ bn2,
    const float* __restrict__ gamma, const float* __restrict__ beta,
    const float* __restrict__ agg_msg, const float* __restrict__ agg_coord,
    const float* __restrict__ cnt, float* __restrict__ out)
{
    const int lane = threadIdx.x & 63;
    const int n = blockIdx.x * 4 + (threadIdx.x >> 6);
    if (n >= N_NODES) return;
    const int j0 = lane * 2;

    const float r0 = h[(size_t)n * 128 + lane];
    const float r1 = h[(size_t)n * 128 + 64 + lane];
    const float r2 = agg_msg[(size_t)n * 128 + lane];
    const float r3 = agg_msg[(size_t)n * 128 + 64 + lane];

    const float2 bn1v = *(const float2*)(bn1 + j0);
    float a0 = bn1v.x, a1 = bn1v.y;
#pragma unroll 8
    for (int k = 0; k < 64; ++k) {
        const float v0 = __shfl(r0, k);
        const float v1 = __shfl(r1, k);
        const float v2 = __shfl(r2, k);
        const float v3 = __shfl(r3, k);
        const float2 w0 = *(const float2*)(Wn1 + (size_t)k * 128 + j0);
        const float2 w1 = *(const float2*)(Wn1 + (size_t)(64 + k) * 128 + j0);
        const float2 w2 = *(const float2*)(Wn1 + (size_t)(128 + k) * 128 + j0);
        const float2 w3 = *(const float2*)(Wn1 + (size_t)(192 + k) * 128 + j0);
        a0 += v0 * w0.x + v1 * w1.x + v2 * w2.x + v3 * w3.x;
        a1 += v0 * w0.y + v1 * w1.y + v2 * w2.y + v3 * w3.y;
    }
    const float z0 = silu(a0), z1 = silu(a1);

    const float2 bn2v = *(const float2*)(bn2 + j0);
    float u0 = bn2v.x, u1 = bn2v.y;
#pragma unroll 8
    for (int q = 0; q < 64; ++q) {
        const float va = __shfl(z0, q);
        const float vb = __shfl(z1, q);
        const float2 w0 = *(const float2*)(Wn2 + (size_t)(2 * q) * 128 + j0);
        const float2 w1 = *(const float2*)(Wn2 + (size_t)(2 * q + 1) * 128 + j0);
        u0 += va * w0.x + vb * w1.x;
        u1 += va * w0.y + vb * w1.y;
    }

    const float2 hv = *(const float2*)(h + (size_t)n * 128 + j0);
    const float y0 = hv.x + u0;
    const float y1 = hv.y + u1;
    float s1 = y0 + y1, s2 = y0 * y0 + y1 * y1;
#pragma unroll
    for (int off = 32; off; off >>= 1) { s1 += __shfl_xor(s1, off); s2 += __shfl_xor(s2, off); }
    const float mu  = s1 * (1.0f / 128.0f);
    const float var = s2 * (1.0f / 128.0f) - mu * mu;
    const float rs  = rsqrtf(var + 1e-5f);
    const float2 gv = *(const float2*)(gamma + j0);
    const float2 bv = *(const float2*)(beta + j0);
    float2 o;
    o.x = (y0 - mu) * rs * gv.x + bv.x;
    o.y = (y1 - mu) * rs * gv.y + bv.y;
    *(float2*)(out + (size_t)n * 128 + j0) = o;

    if (lane < 3) {
        const float c = fmaxf(cnt[n], 1.0f);
        out[(size_t)N_NODES * 128 + (size_t)n * 3 + lane] =
            x[n * 3 + lane] + agg_coord[n * 3 + lane] / c;
    }
}

extern "C" void kernel_launch(void* const* d_in, const int* in_sizes, int n_in,
                              void* d_out, int out_size, void* d_ws, size_t ws_size,
                              hipStream_t stream)
{
    const float* h     = (const float*)d_in[0];
    const float* x     = (const float*)d_in[1];
    const int*   ei    = (const int*)d_in[2];
    const float* eattr = (const float*)d_in[3];
    const float* W1    = (const float*)d_in[4];
    const float* b1    = (const float*)d_in[5];
    const float* W2    = (const float*)d_in[6];
    const float* b2    = (const float*)d_in[7];
    const float* Wc1   = (const float*)d_in[8];
    const float* bc1   = (const float*)d_in[9];
    const float* Wc2   = (const float*)d_in[10];
    const float* bc2   = (const float*)d_in[11];
    const float* Wn1   = (const float*)d_in[12];
    const float* bn1   = (const float*)d_in[13];
    const float* Wn2   = (const float*)d_in[14];
    const float* bn2   = (const float*)d_in[15];
    const float* gamma = (const float*)d_in[16];
    const float* beta  = (const float*)d_in[17];

    // ws layout (~52.1 MB):
    //   A        : N*64 uint32 (f16x2)
    //   B        : N*64 uint32 (f16x2)
    //   agg_msg  : N*128 f32 (zeroed)
    //   agg_coord: N*3 f32   (zeroed)
    //   cnt      : N f32     (zeroed)
    //   W2A,WC1A : 8192 uint32 each (A-frag f16 weights)
    uint32* A        = (uint32*)d_ws;
    uint32* B        = A + (size_t)N_NODES * 64;
    float* agg_msg   = (float*)(B + (size_t)N_NODES * 64);
    float* agg_coord = agg_msg + (size_t)N_NODES * 128;
    float* cnt       = agg_coord + (size_t)N_NODES * 3;
    uint32* W2A      = (uint32*)(cnt + N_NODES);
    uint32* WC1A     = W2A + 8192;

    const int zero_elems = N_NODES * 128 + N_NODES * 3 + N_NODES;
    zero_ws<<<512, 256, 0, stream>>>(agg_msg, zero_elems);
    prep_frags<<<32, 256, 0, stream>>>(W2, Wc1, W2A, WC1A);
    pre_proj<<<(N_NODES + 3) / 4, 256, 0, stream>>>(h, W1, A, B);
    edge_mfma<<<1024, 256, 0, stream>>>(ei, x, eattr, W1, b1, b2, bc1, Wc2, bc2,
                                        W2A, WC1A, A, B, agg_msg, agg_coord, cnt);
    node_kernel<<<(N_NODES + 3) / 4, 256, 0, stream>>>(h, x, Wn1, bn1, Wn2, bn2,
                                                       gamma, beta, agg_msg, agg_coord,
                                                       cnt, (float*)d_out);
}

// Round 10
// 1567.517 us; speedup vs baseline: 2.5197x; 1.5739x over previous
//
#include <hip/hip_runtime.h>
#include <hip/hip_bf16.h>
#include <stdint.h>

#define N_NODES 50000
#define N_EDGES 800000
#define N_TILES (N_EDGES / 16)

typedef unsigned int uint32;
typedef __fp16   fp16x2 __attribute__((ext_vector_type(2)));
typedef _Float16 half8v __attribute__((ext_vector_type(8)));
typedef float    f32x4  __attribute__((ext_vector_type(4)));
typedef uint32   u32x2  __attribute__((ext_vector_type(2)));
typedef uint32   u32x4  __attribute__((ext_vector_type(4)));

union H2U { uint32 u; fp16x2 h; };
union H8U { u32x4 u; half8v h; };

__device__ __forceinline__ uint32 pk16(float lo, float hi) {
    H2U z; z.h = __builtin_amdgcn_cvt_pkrtz(lo, hi); return z.u;
}
__device__ __forceinline__ float h16lo(uint32 u) { H2U z; z.u = u; return (float)z.h[0]; }
__device__ __forceinline__ float h16hi(uint32 u) { H2U z; z.u = u; return (float)z.h[1]; }
__device__ __forceinline__ float silu(float v) { return v / (1.0f + __expf(-v)); }

// ---------- Kernel 0: zero aggregation buffers ------------------------------
__global__ __launch_bounds__(256) void zero_ws(float* __restrict__ p, int n) {
    int i = blockIdx.x * 256 + threadIdx.x;
    int stride = gridDim.x * 256;
    for (; i < n; i += stride) p[i] = 0.0f;
}

// ---------- Kernel 0b: weight fragments (f16x2) in ws -----------------------
// W2A/WC1A: frag f = ot*4+kb; entry ((f*64+lane)*4+p) = (W[k0][o], W[k0+1][o]),
// k0 = kb*32 + (lane>>4)*8 + 2p, o = (lane&15)+16*ot.
// W1TF: 5 packed rows (W1[256..259], b1) of 64 u32 each, pair p = ch (2p,2p+1).
__global__ __launch_bounds__(256) void prep_frags(
    const float* __restrict__ W2, const float* __restrict__ Wc1,
    const float* __restrict__ W1, const float* __restrict__ b1,
    uint32* __restrict__ W2A, uint32* __restrict__ WC1A, uint32* __restrict__ W1TF)
{
    int i = blockIdx.x * 256 + threadIdx.x;
    if (i < 8192) {
        const int p = i & 3, l = (i >> 2) & 63, f = i >> 8;
        const int ot = f >> 2, kb = f & 3;
        const int k0 = kb * 32 + (l >> 4) * 8 + 2 * p;
        const int o  = (l & 15) + ot * 16;
        W2A[i]  = pk16(W2[(size_t)k0 * 128 + o],  W2[(size_t)(k0 + 1) * 128 + o]);
        WC1A[i] = pk16(Wc1[(size_t)k0 * 128 + o], Wc1[(size_t)(k0 + 1) * 128 + o]);
    }
    if (i < 5 * 64) {
        const int row = i >> 6, p = i & 63;
        if (row < 4)
            W1TF[i] = pk16(W1[(size_t)(256 + row) * 128 + 2 * p],
                           W1[(size_t)(256 + row) * 128 + 2 * p + 1]);
        else
            W1TF[i] = pk16(b1[2 * p], b1[2 * p + 1]);
    }
}

// ---------- Kernel 1: A = h@W1[0:128], B = h@W1[128:256]  (4 nodes/wave) ----
__global__ __launch_bounds__(256) void pre_proj(
    const float* __restrict__ h, const float* __restrict__ W1,
    uint32* __restrict__ A, uint32* __restrict__ B)
{
    const int lane = threadIdx.x & 63;
    const int wave = blockIdx.x * 4 + (threadIdx.x >> 6);
    const int n0 = wave * 4;
    if (n0 >= N_NODES) return;
    const int j0 = lane * 2;

    float ha[4], hb[4];
#pragma unroll
    for (int i = 0; i < 4; ++i) {
        ha[i] = h[(size_t)(n0 + i) * 128 + lane];
        hb[i] = h[(size_t)(n0 + i) * 128 + 64 + lane];
    }
    float2 accA[4], accB[4];
#pragma unroll
    for (int i = 0; i < 4; ++i) { accA[i] = make_float2(0.f, 0.f); accB[i] = make_float2(0.f, 0.f); }

#pragma unroll 8
    for (int k = 0; k < 64; ++k) {
        const float2 wa0 = *(const float2*)(W1 + (size_t)k * 128 + j0);
        const float2 wa1 = *(const float2*)(W1 + (size_t)(64 + k) * 128 + j0);
        const float2 wb0 = *(const float2*)(W1 + (size_t)(128 + k) * 128 + j0);
        const float2 wb1 = *(const float2*)(W1 + (size_t)(192 + k) * 128 + j0);
#pragma unroll
        for (int i = 0; i < 4; ++i) {
            const float va = __shfl(ha[i], k);
            const float vb = __shfl(hb[i], k);
            accA[i].x += va * wa0.x + vb * wa1.x;
            accA[i].y += va * wa0.y + vb * wa1.y;
            accB[i].x += va * wb0.x + vb * wb1.x;
            accB[i].y += va * wb0.y + vb * wb1.y;
        }
    }
#pragma unroll
    for (int i = 0; i < 4; ++i) {
        A[(size_t)(n0 + i) * 64 + lane] = pk16(accA[i].x, accA[i].y);
        B[(size_t)(n0 + i) * 64 + lane] = pk16(accB[i].x, accB[i].y);
    }
}

// ---------- Kernel 2: MFMA edge kernel, pipelined ---------------------------
// lane = (quad, e_own): edge-major fragment layout. Direct B-frag gathers from
// Apk/Bpk (no broadcast loop). Next tile's gathers issue BEFORE this tile's
// atomics so the compiler can wait with vmcnt(N>0) instead of a full drain.
#define EWAVES 4
__global__ __launch_bounds__(256, 3) void edge_mfma(
    const int* __restrict__ ei, const float* __restrict__ x,
    const float* __restrict__ eattr,
    const float* __restrict__ b2, const float* __restrict__ bc1,
    const float* __restrict__ Wc2, const float* __restrict__ bc2,
    const uint32* __restrict__ W2A, const uint32* __restrict__ WC1A,
    const uint32* __restrict__ W1TF,
    const uint32* __restrict__ Apk, const uint32* __restrict__ Bpk,
    float* __restrict__ agg_msg, float* __restrict__ agg_coord, float* __restrict__ cnt)
{
    __shared__ uint32 sM2[EWAVES * 16 * 68];   // per-wave m2 transpose staging

    const int tid   = threadIdx.x;
    const int lane  = tid & 63;
    const int wv    = tid >> 6;
    const int quad  = lane >> 4;
    const int e_own = lane & 15;
    const int swb   = wv * (16 * 68);
    const float bc2f = bc2[0];

    const int wave = blockIdx.x * EWAVES + wv;
    const int nw   = gridDim.x * EWAVES;

    int t = wave;
    if (t >= N_TILES) return;

    // pipeline registers ("n" = tile whose m1 is being prepared)
    int nsrc, ndst; float nrx, nry, nrz, ndsq, ne0, ne1, ne2;
    u32x4 av[4], bv[4];
    half8v m1h[4];

    auto load_tile = [&](int tt) {
        const int eidx = tt * 16 + e_own;
        nsrc = ei[eidx];
        ndst = ei[N_EDGES + eidx];
        nrx = x[nsrc * 3 + 0] - x[ndst * 3 + 0];
        nry = x[nsrc * 3 + 1] - x[ndst * 3 + 1];
        nrz = x[nsrc * 3 + 2] - x[ndst * 3 + 2];
        ndsq = nrx * nrx + nry * nry + nrz * nrz;
        ne0 = eattr[(size_t)eidx * 3 + 0];
        ne1 = eattr[(size_t)eidx * 3 + 1];
        ne2 = eattr[(size_t)eidx * 3 + 2];
#pragma unroll
        for (int kb = 0; kb < 4; ++kb) {
            av[kb] = *(const u32x4*)&Apk[(size_t)nsrc * 64 + kb * 16 + quad * 4];
            bv[kb] = *(const u32x4*)&Bpk[(size_t)ndst * 64 + kb * 16 + quad * 4];
        }
    };

    auto compute_m1 = [&]() {
        const _Float16 s0 = (_Float16)ne0, s1 = (_Float16)ne1;
        const _Float16 s2 = (_Float16)ne2, sd = (_Float16)ndsq;
#pragma unroll
        for (int kb = 0; kb < 4; ++kb) {
            const int base = kb * 16 + quad * 4;
            H8U a, b, w0, w1, w2, w3, w4;
            a.u  = av[kb]; b.u = bv[kb];
            w0.u = *(const u32x4*)&W1TF[0 * 64 + base];
            w1.u = *(const u32x4*)&W1TF[1 * 64 + base];
            w2.u = *(const u32x4*)&W1TF[2 * 64 + base];
            w3.u = *(const u32x4*)&W1TF[3 * 64 + base];
            w4.u = *(const u32x4*)&W1TF[4 * 64 + base];
            half8v s = a.h + b.h + w4.h;
            s += w0.h * s0;
            s += w1.h * s1;
            s += w2.h * s2;
            s += w3.h * sd;
            half8v m;
#pragma unroll
            for (int j = 0; j < 8; ++j) m[j] = (_Float16)silu((float)s[j]);
            m1h[kb] = m;
        }
    };

    load_tile(t);
    compute_m1();

    while (t < N_TILES) {
        const int   src_own = nsrc, dst_own = ndst;
        const float rxo = nrx, ryo = nry, rzo = nrz;
        const int   tn = t + nw;
        const bool  more = (tn < N_TILES);
        if (more) load_tile(tn);            // gathers issue BEFORE atomics below

        // ---- matmul 1: D1[o][e] = sum_k W2[k][o] * m1[e][k] ----------------
        f32x4 acc[8];
#pragma unroll
        for (int ot = 0; ot < 8; ++ot) acc[ot] = 0.0f;
#pragma unroll 2
        for (int ot = 0; ot < 8; ++ot) {
#pragma unroll
            for (int kb = 0; kb < 4; ++kb) {
                H8U w; w.u = *(const u32x4*)(W2A + (size_t)((ot * 4 + kb) * 64 + lane) * 4);
                acc[ot] = __builtin_amdgcn_mfma_f32_16x16x32_f16(w.h, m1h[kb], acc[ot], 0, 0, 0);
            }
        }

        // ---- epilogue 1: m2 = silu(D1+b2) -> LDS transpose stage -----------
#pragma unroll
        for (int ot = 0; ot < 8; ++ot) {
            const f32x4 bb = *(const f32x4*)(b2 + 16 * ot + 4 * quad);
            const float m0  = silu(acc[ot][0] + bb[0]);
            const float m1_ = silu(acc[ot][1] + bb[1]);
            const float m2_ = silu(acc[ot][2] + bb[2]);
            const float m3_ = silu(acc[ot][3] + bb[3]);
            u32x2 pair;
            pair[0] = pk16(m0, m1_);
            pair[1] = pk16(m2_, m3_);
            *(u32x2*)&sM2[swb + e_own * 68 + 8 * ot + 2 * quad] = pair;
        }

        // ---- B-frags of m2^T ----------------------------------------------
        H8U m2f[4];
#pragma unroll
        for (int kb = 0; kb < 4; ++kb)
            m2f[kb].u = *(const u32x4*)&sM2[swb + e_own * 68 + kb * 16 + quad * 4];

        // ---- matmul 2: D2[o2][e] = sum_k Wc1[k][o2] * m2[e][k] -------------
#pragma unroll
        for (int ot = 0; ot < 8; ++ot) acc[ot] = 0.0f;
#pragma unroll 2
        for (int ot = 0; ot < 8; ++ot) {
#pragma unroll
            for (int kb = 0; kb < 4; ++kb) {
                H8U w; w.u = *(const u32x4*)(WC1A + (size_t)((ot * 4 + kb) * 64 + lane) * 4);
                acc[ot] = __builtin_amdgcn_mfma_f32_16x16x32_f16(w.h, m2f[kb].h, acc[ot], 0, 0, 0);
            }
        }

        // ---- coalesced agg_msg atomics (full 512B row per edge) ------------
#pragma unroll
        for (int e = 0; e < 16; ++e) {
            const int de = __shfl(dst_own, e);
            const uint32 v = sM2[swb + e * 68 + lane];
            atomicAdd(&agg_msg[(size_t)de * 128 + 2 * lane],     h16lo(v));
            atomicAdd(&agg_msg[(size_t)de * 128 + 2 * lane + 1], h16hi(v));
        }

        // ---- epilogue 2: t = silu(D2+bc1); cw = t.Wc2 + bc2; coord ---------
        float partial = 0.0f;
#pragma unroll
        for (int ot = 0; ot < 8; ++ot) {
            const f32x4 bb = *(const f32x4*)(bc1 + 16 * ot + 4 * quad);
            const f32x4 wc = *(const f32x4*)(Wc2 + 16 * ot + 4 * quad);
#pragma unroll
            for (int r = 0; r < 4; ++r)
                partial += silu(acc[ot][r] + bb[r]) * wc[r];
        }
        partial += __shfl_xor(partial, 16);
        partial += __shfl_xor(partial, 32);
        const float cw = partial + bc2f;

        if (quad < 3) {
            const float rsel = (quad == 0) ? rxo : ((quad == 1) ? ryo : rzo);
            atomicAdd(&agg_coord[dst_own * 3 + quad], rsel * cw);
        } else {
            atomicAdd(&cnt[dst_own], 1.0f);
        }

        if (more) compute_m1();             // waits on gathers (older than atomics)
        t = tn;
    }
}

// ---------- Kernel 3: node MLP + layernorm + x_out  (4 nodes/wave) ----------
__global__ __launch_bounds__(256) void node_kernel(
    const float* __restrict__ h, const float* __restrict__ x,
    const float* __restrict__ Wn1, const float* __restrict__ bn1,
    const float* __restrict__ Wn2, const float* __restrict__ bn2,
    const float* __restrict__ gamma, const float* __restrict__ beta,
    const float* __restrict__ agg_msg, const float* __restrict__ agg_coord,
    const float* __restrict__ cnt, float* __restrict__ out)
{
    const int lane = threadIdx.x & 63;
    const int wave = blockIdx.x * 4 + (threadIdx.x >> 6);
    const int n0 = wave * 4;
    if (n0 >= N_NODES) return;
    const int j0 = lane * 2;

    float r0[4], r1[4], r2[4], r3[4];
#pragma unroll
    for (int i = 0; i < 4; ++i) {
        r0[i] = h[(size_t)(n0 + i) * 128 + lane];
        r1[i] = h[(size_t)(n0 + i) * 128 + 64 + lane];
        r2[i] = agg_msg[(size_t)(n0 + i) * 128 + lane];
        r3[i] = agg_msg[(size_t)(n0 + i) * 128 + 64 + lane];
    }

    const float2 bn1v = *(const float2*)(bn1 + j0);
    float2 a[4];
#pragma unroll
    for (int i = 0; i < 4; ++i) { a[i].x = bn1v.x; a[i].y = bn1v.y; }

#pragma unroll 8
    for (int k = 0; k < 64; ++k) {
        const float2 w0 = *(const float2*)(Wn1 + (size_t)k * 128 + j0);
        const float2 w1 = *(const float2*)(Wn1 + (size_t)(64 + k) * 128 + j0);
        const float2 w2 = *(const float2*)(Wn1 + (size_t)(128 + k) * 128 + j0);
        const float2 w3 = *(const float2*)(Wn1 + (size_t)(192 + k) * 128 + j0);
#pragma unroll
        for (int i = 0; i < 4; ++i) {
            const float v0 = __shfl(r0[i], k);
            const float v1 = __shfl(r1[i], k);
            const float v2 = __shfl(r2[i], k);
            const float v3 = __shfl(r3[i], k);
            a[i].x += v0 * w0.x + v1 * w1.x + v2 * w2.x + v3 * w3.x;
            a[i].y += v0 * w0.y + v1 * w1.y + v2 * w2.y + v3 * w3.y;
        }
    }

    float2 z[4];
#pragma unroll
    for (int i = 0; i < 4; ++i) { z[i].x = silu(a[i].x); z[i].y = silu(a[i].y); }

    const float2 bn2v = *(const float2*)(bn2 + j0);
    float2 u[4];
#pragma unroll
    for (int i = 0; i < 4; ++i) { u[i].x = bn2v.x; u[i].y = bn2v.y; }

#pragma unroll 8
    for (int q = 0; q < 64; ++q) {
        const float2 w0 = *(const float2*)(Wn2 + (size_t)(2 * q) * 128 + j0);
        const float2 w1 = *(const float2*)(Wn2 + (size_t)(2 * q + 1) * 128 + j0);
#pragma unroll
        for (int i = 0; i < 4; ++i) {
            const float va = __shfl(z[i].x, q);
            const float vb = __shfl(z[i].y, q);
            u[i].x += va * w0.x + vb * w1.x;
            u[i].y += va * w0.y + vb * w1.y;
        }
    }

    const float2 gv = *(const float2*)(gamma + j0);
    const float2 bv = *(const float2*)(beta + j0);
#pragma unroll
    for (int i = 0; i < 4; ++i) {
        const float2 hv = *(const float2*)(h + (size_t)(n0 + i) * 128 + j0);
        const float y0 = hv.x + u[i].x;
        const float y1 = hv.y + u[i].y;
        float s1 = y0 + y1, s2 = y0 * y0 + y1 * y1;
#pragma unroll
        for (int off = 32; off; off >>= 1) { s1 += __shfl_xor(s1, off); s2 += __shfl_xor(s2, off); }
        const float mu  = s1 * (1.0f / 128.0f);
        const float var = s2 * (1.0f / 128.0f) - mu * mu;
        const float rs  = rsqrtf(var + 1e-5f);
        float2 o;
        o.x = (y0 - mu) * rs * gv.x + bv.x;
        o.y = (y1 - mu) * rs * gv.y + bv.y;
        *(float2*)(out + (size_t)(n0 + i) * 128 + j0) = o;
    }

    const int g = lane >> 4, r = lane & 15;
    if (r < 3) {
        const int n = n0 + g;
        const float c = fmaxf(cnt[n], 1.0f);
        out[(size_t)N_NODES * 128 + (size_t)n * 3 + r] =
            x[n * 3 + r] + agg_coord[n * 3 + r] / c;
    }
}

extern "C" void kernel_launch(void* const* d_in, const int* in_sizes, int n_in,
                              void* d_out, int out_size, void* d_ws, size_t ws_size,
                              hipStream_t stream)
{
    const float* h     = (const float*)d_in[0];
    const float* x     = (const float*)d_in[1];
    const int*   ei    = (const int*)d_in[2];
    const float* eattr = (const float*)d_in[3];
    const float* W1    = (const float*)d_in[4];
    const float* b1    = (const float*)d_in[5];
    const float* W2    = (const float*)d_in[6];
    const float* b2    = (const float*)d_in[7];
    const float* Wc1   = (const float*)d_in[8];
    const float* bc1   = (const float*)d_in[9];
    const float* Wc2   = (const float*)d_in[10];
    const float* bc2   = (const float*)d_in[11];
    const float* Wn1   = (const float*)d_in[12];
    const float* bn1   = (const float*)d_in[13];
    const float* Wn2   = (const float*)d_in[14];
    const float* bn2   = (const float*)d_in[15];
    const float* gamma = (const float*)d_in[16];
    const float* beta  = (const float*)d_in[17];

    // ws layout (~52.1 MB)
    uint32* A        = (uint32*)d_ws;                      // N*64 u32 (f16x2)
    uint32* B        = A + (size_t)N_NODES * 64;           // N*64 u32
    float* agg_msg   = (float*)(B + (size_t)N_NODES * 64); // N*128 f32 (zeroed)
    float* agg_coord = agg_msg + (size_t)N_NODES * 128;    // N*3 (zeroed)
    float* cnt       = agg_coord + (size_t)N_NODES * 3;    // N (zeroed)
    uint32* W2A      = (uint32*)(cnt + N_NODES);           // 8192 u32
    uint32* WC1A     = W2A + 8192;                         // 8192 u32
    uint32* W1TF     = WC1A + 8192;                        // 320 u32

    const int zero_elems = N_NODES * 128 + N_NODES * 3 + N_NODES;
    zero_ws<<<512, 256, 0, stream>>>(agg_msg, zero_elems);
    prep_frags<<<32, 256, 0, stream>>>(W2, Wc1, W1, b1, W2A, WC1A, W1TF);
    pre_proj<<<3125, 256, 0, stream>>>(h, W1, A, B);
    edge_mfma<<<1024, 256, 0, stream>>>(ei, x, eattr, b2, bc1, Wc2, bc2,
                                        W2A, WC1A, W1TF, A, B,
                                        agg_msg, agg_coord, cnt);
    node_kernel<<<3125, 256, 0, stream>>>(h, x, Wn1, bn1, Wn2, bn2,
                                          gamma, beta, agg_msg, agg_coord,
                                          cnt, (float*)d_out);
}